// Round 12
// baseline (190.405 us; speedup 1.0000x reference)
//
#include <hip/hip_runtime.h>

// ---------------------------------------------------------------------------
// QuantizedLinear: y = x @ ((q - zp)*s)^T + bias    — INT8 MFMA path.
// Per-row x quant: s_x[m] = max|x[m,:]|/127, xq = rint(x/s_x)  (s8)
// Weight: qs8 = q - 128 (exact).  EXACT given quantized x:
//   y[m,o] = s_x[m]*s[o]*( G8[m,o] + (128-zp[o])*rq[m] ) + bias[o]
// Round 12: back to 16x16x64 MFMA (R11's 32x32 broke the swizzle: 13.1M
// bank conflicts). NEW: 4-wave (256-thread) blocks, BM=256 BN=128 BK=64,
// LDS 48 KiB -> 2 blocks/CU (regs: 1 wave/SIMD/block x ~230 -> 2 fit;
// R8/R10's 512-thread blocks were register-blocked at 1 block/CU).
// Two co-resident blocks give uncorrelated barrier schedules per SIMD ->
// cross-block MFMA||LDS overlap (m114).
// Ledger (per-wave GLDS: A(t+1)[4 @ t-1 p1], B(t+1)[2 @ t p0],
// A(t+2)[4 @ t p1] = 10 outstanding at tile end):
//  p0: read a0-7,b0-1 |fence| b2-3 | stage B(t+1) | lgkm(2) | q0 m0-7 x n0-1
//  p1: lgkm(0) | B2 (WAR: buf-d reads done) | stage A(t+2) | q1 m0-7 x n2-3
//  end: vmcnt(4) steady / vmcnt(0) t>=NT-2 | B3 (RAW: t+1 landed)
// Staging swizzle (64-B rows, 4 slots): phys = slot ^ (row&3) -> max 2-way
// (free, m136); read addr (g ^ (fr&3))*16.
// ---------------------------------------------------------------------------

typedef unsigned char u8;
typedef signed char s8;
typedef __attribute__((ext_vector_type(4))) int i32x4;
typedef __attribute__((ext_vector_type(4))) float f32x4;

#define M_TOK 8192
#define KDIM 4096
#define NDIM 4096
#define NT (KDIM / 64)  // 64 K-tiles of 64 i8

// --- helpers ---------------------------------------------------------------

__device__ __forceinline__ int pack4(int a, int b, int c, int d) {
  return (a & 255) | ((b & 255) << 8) | ((c & 255) << 16) |
         (int)(((unsigned)(d & 255)) << 24);
}

#define GLDS(gptr, lptr)                                                      \
  __builtin_amdgcn_global_load_lds(                                          \
      (const __attribute__((address_space(1))) void*)(gptr),                 \
      (__attribute__((address_space(3))) void*)(lptr), 16, 0, 0)

// --- kernel 1: x f32 -> s8 per-row quant, fused row max + row sum ----------

__global__ __launch_bounds__(256) void convert_x_kernel(
    const float* __restrict__ x, s8* __restrict__ xq,
    float* __restrict__ sx, float* __restrict__ rq) {
  const int row = blockIdx.x;
  const int tid = threadIdx.x;
  const float* xr = x + (size_t)row * KDIM + tid * 16;
  float4 v[4];
#pragma unroll
  for (int i = 0; i < 4; ++i) v[i] = ((const float4*)xr)[i];

  float mx = 0.f;
#pragma unroll
  for (int i = 0; i < 4; ++i) {
    mx = fmaxf(mx, fabsf(v[i].x)); mx = fmaxf(mx, fabsf(v[i].y));
    mx = fmaxf(mx, fabsf(v[i].z)); mx = fmaxf(mx, fabsf(v[i].w));
  }
#pragma unroll
  for (int off = 32; off > 0; off >>= 1)
    mx = fmaxf(mx, __shfl_down(mx, off, 64));
  __shared__ float redf[4];
  __shared__ float bmax;
  if ((tid & 63) == 0) redf[tid >> 6] = mx;
  __syncthreads();
  if (tid == 0)
    bmax = fmaxf(fmaxf(redf[0], redf[1]), fmaxf(redf[2], redf[3]));
  __syncthreads();
  const float maxv = bmax;
  const float inv = 127.0f / fmaxf(maxv, 1e-30f);

  int q[16];
  int ssum = 0;
#pragma unroll
  for (int i = 0; i < 4; ++i) {
    q[i * 4 + 0] = (int)rintf(v[i].x * inv);
    q[i * 4 + 1] = (int)rintf(v[i].y * inv);
    q[i * 4 + 2] = (int)rintf(v[i].z * inv);
    q[i * 4 + 3] = (int)rintf(v[i].w * inv);
  }
#pragma unroll
  for (int i = 0; i < 16; ++i) ssum += q[i];

  int4 o;
  o.x = pack4(q[0], q[1], q[2], q[3]);
  o.y = pack4(q[4], q[5], q[6], q[7]);
  o.z = pack4(q[8], q[9], q[10], q[11]);
  o.w = pack4(q[12], q[13], q[14], q[15]);
  *(int4*)(xq + (size_t)row * KDIM + tid * 16) = o;

#pragma unroll
  for (int off = 32; off > 0; off >>= 1) ssum += __shfl_down(ssum, off, 64);
  __shared__ int redi[4];
  if ((tid & 63) == 0) redi[tid >> 6] = ssum;
  __syncthreads();
  if (tid == 0) {
    sx[row] = maxv * (1.0f / 127.0f);
    rq[row] = (float)(redi[0] + redi[1] + redi[2] + redi[3]);  // < 2^24 exact
  }
}

// --- kernel 2: w int32 -> s8 (q - 128, exact) --------------------------------

__global__ __launch_bounds__(256) void convert_w_kernel(
    const int* __restrict__ wq, s8* __restrict__ wb) {
  const size_t idx = (size_t)blockIdx.x * 256 + threadIdx.x;  // 16 elems each
  const int4* src = (const int4*)wq + idx * 4;
  const int4 a = src[0], b = src[1], c = src[2], d = src[3];
  int4 o;
  o.x = pack4(a.x - 128, a.y - 128, a.z - 128, a.w - 128);
  o.y = pack4(b.x - 128, b.y - 128, b.z - 128, b.w - 128);
  o.z = pack4(c.x - 128, c.y - 128, c.z - 128, c.w - 128);
  o.w = pack4(d.x - 128, d.y - 128, d.z - 128, d.w - 128);
  ((int4*)wb)[idx] = o;
}

// --- kernel 3: 256x128 i8 GEMM, BK=64, 4 waves, 2 blocks/CU -----------------

__global__ __launch_bounds__(256, 2) void qlin_gemm_kernel(
    const u8* __restrict__ A,         // [M][K] s8 bits
    const u8* __restrict__ B,         // [N][K] s8 bits
    const float* __restrict__ sx,     // [M]
    const float* __restrict__ rq,     // [M]
    const float* __restrict__ scale,  // [N]
    const float* __restrict__ zp,     // [N]
    const float* __restrict__ bias,   // [N]
    float* __restrict__ out) {        // [M][N]
  extern __shared__ u8 lds[];
  u8* Al = lds;           // [2][256][64]  = 32 KiB
  u8* Bl = lds + 32768;   // [2][128][64]  = 16 KiB

  const int tid = threadIdx.x;
  const int lane = tid & 63;
  const int wave = tid >> 6;  // 0..3
  const int wm = wave >> 1;   // 0..1  (128-row half)
  const int wn = wave & 1;    // 0..1  (64-col half)

  // T1: bijective XCD swizzle (1024 wgs, 1024%8==0)
  const int bid = blockIdx.x;
  const int swz = (bid & 7) * 128 + (bid >> 3);
  const int bm = swz >> 5;    // 0..31
  const int bn = swz & 31;    // 0..31
  const int row0 = bm * 256, col0 = bn * 128;

  // staging: lane l -> chunk row l>>2, phys slot l&3; fetch logical slot
  // (l&3)^(row&3) (pre-swizzled source; GLDS dest wave-uniform + l*16).
  const int srow = lane >> 2;
  const int sslot = (lane & 3) ^ (srow & 3);
  const u8* Ags = A + (size_t)(row0 + wave * 64 + srow) * KDIM + sslot * 16;
  const u8* Bgs = B + (size_t)(col0 + wave * 32 + srow) * KDIM + sslot * 16;
  u8* AldW = Al + wave * 4096;  // 4 chunks of 1024 B
  u8* BldW = Bl + wave * 2048;  // 2 chunks

#define STAGE_A(d, tau)                                                       \
  do {                                                                        \
    _Pragma("unroll") for (int i = 0; i < 4; ++i)                             \
        GLDS(Ags + (size_t)i * 16 * KDIM + (size_t)(tau) * 64,               \
             AldW + (d) * 16384 + i * 1024);                                 \
  } while (0)

#define STAGE_B(d, tau)                                                       \
  do {                                                                        \
    _Pragma("unroll") for (int j = 0; j < 2; ++j)                             \
        GLDS(Bgs + (size_t)j * 16 * KDIM + (size_t)(tau) * 64,               \
             BldW + (d) * 8192 + j * 1024);                                  \
  } while (0)

  // fragment reads: lane (fr=lane&15, g=lane>>4) reads row <dim0>+fr,
  // phys slot g^(fr&3) (row&3 == fr&3 since row offsets are mult of 16).
  const int fr = lane & 15;
  const int g = lane >> 4;
  const int sw = ((g ^ (fr & 3)) << 4);
  const u8* Ar = Al + (wm * 128 + fr) * 64 + sw;
  const u8* Br = Bl + (wn * 64 + fr) * 64 + sw;

#define LDA(d, m) (*(const i32x4*)(Ar + (d) * 16384 + (m) * 1024))
#define LDB(d, n) (*(const i32x4*)(Br + (d) * 8192 + (n) * 1024))
#define MFMA(d, va, vb) \
  d = __builtin_amdgcn_mfma_i32_16x16x64_i8(va, vb, d, 0, 0, 0)

  i32x4 acc[8][4] = {};
  i32x4 a[8], b[4];

  // prologue: A(0) 4, B(0) 2, A(1) 4 = 10 GLDS; vmcnt(4) -> tile0 landed,
  // A(1)'s 4 in flight.
  STAGE_A(0, 0);
  STAGE_B(0, 0);
  STAGE_A(1, 1);
  asm volatile("s_waitcnt vmcnt(4)" ::: "memory");
  __builtin_amdgcn_s_barrier();

  for (int t = 0; t < NT; ++t) {
    const int d = t & 1;

    // ---- p0: read a0-7, b0-1 | fence | b2-3 | stage B(t+1) | lgkm(2) |
    //      q0: m0-7 x n0-1 ----
#pragma unroll
    for (int m = 0; m < 8; ++m) a[m] = LDA(d, m);
    b[0] = LDB(d, 0); b[1] = LDB(d, 1);
    asm volatile("" ::: "memory");  // pin {a0-7,b0-1} before {b2-3}
    b[2] = LDB(d, 2); b[3] = LDB(d, 3);
    if (t + 1 < NT) STAGE_B(d ^ 1, t + 1);
    asm volatile("s_waitcnt lgkmcnt(2)" ::: "memory");  // a0-7 + b0-1 ready
    __builtin_amdgcn_s_setprio(1);
#pragma unroll
    for (int m = 0; m < 8; ++m)
#pragma unroll
      for (int n = 0; n < 2; ++n) MFMA(acc[m][n], a[m], b[n]);
    __builtin_amdgcn_s_setprio(0);

    // ---- p1: lgkm(0) | B2 (WAR: all waves' buf-d reads done) |
    //      stage A(t+2) into buf d | q1: m0-7 x n2-3 ----
    asm volatile("s_waitcnt lgkmcnt(0)" ::: "memory");
    __builtin_amdgcn_s_barrier();  // B2
    if (t + 2 < NT) STAGE_A(d, t + 2);
    __builtin_amdgcn_s_setprio(1);
#pragma unroll
    for (int m = 0; m < 8; ++m)
#pragma unroll
      for (int n = 2; n < 4; ++n) MFMA(acc[m][n], a[m], b[n]);
    __builtin_amdgcn_s_setprio(0);

    // ---- tile end: vmcnt | B3 (RAW: A(t+1),B(t+1) landed chip-wide) ----
    if (t < NT - 2) {
      asm volatile("s_waitcnt vmcnt(4)" ::: "memory");  // keep A(t+2) flying
    } else {
      asm volatile("s_waitcnt vmcnt(0)" ::: "memory");  // tail drain
    }
    __builtin_amdgcn_s_barrier();  // B3
  }

  // --- epilogue: i32->f32, per-wave LDS transpose, coalesced f32x4 stores ---
  // C/D 16x16: col = lane&15 (=fr), row = g*4 + reg.
  // y = sx[row]*( s[col]*G + s[col]*(128-zp[col])*rq[row] ) + bias[col]
  {
    const int wrow0 = row0 + wm * 128;
    const int wcol0 = col0 + wn * 64;
    float* eps = (float*)lds + wave * 2176;  // 32x68 f32, wave-private
    const f32x4 p4 = *(const f32x4*)(scale + wcol0 + 4 * fr);
    const f32x4 z4 = *(const f32x4*)(zp + wcol0 + 4 * fr);
    const f32x4 b4 = *(const f32x4*)(bias + wcol0 + 4 * fr);
    const f32x4 w04 = p4 * (128.0f - z4);
#pragma unroll
    for (int c = 0; c < 4; ++c) {
#pragma unroll
      for (int mm = 0; mm < 2; ++mm)
#pragma unroll
        for (int n = 0; n < 4; ++n)
#pragma unroll
          for (int q = 0; q < 4; ++q)
            eps[(mm * 16 + g * 4 + q) * 68 + n * 16 + fr] =
                (float)acc[2 * c + mm][n][q];
      asm volatile("s_waitcnt lgkmcnt(0)" ::: "memory");
#pragma unroll
      for (int j = 0; j < 8; ++j) {
        const int rl = j * 4 + g;                 // 0..31
        const int grow = wrow0 + c * 32 + rl;
        const f32x4 v = *(const f32x4*)(eps + rl * 68 + 4 * fr);
        const float sxr = sx[grow];
        const float rqr = rq[grow];
        const f32x4 o4 = sxr * (p4 * v + w04 * rqr) + b4;
        *(f32x4*)(out + (size_t)grow * NDIM + wcol0 + 4 * fr) = o4;
      }
      asm volatile("s_waitcnt lgkmcnt(0)" ::: "memory");  // WAR before reuse
    }
  }
#undef STAGE_A
#undef STAGE_B
#undef LDA
#undef LDB
#undef MFMA
}

// --- launch ------------------------------------------------------------------

extern "C" void kernel_launch(void* const* d_in, const int* in_sizes, int n_in,
                              void* d_out, int out_size, void* d_ws,
                              size_t ws_size, hipStream_t stream) {
  const float* x = (const float*)d_in[0];
  const int* wq = (const int*)d_in[1];
  const float* scale = (const float*)d_in[2];
  const float* zp = (const float*)d_in[3];
  const float* bias = (const float*)d_in[4];
  float* out = (float*)d_out;

  // workspace: xq 32 MiB | wq8 16 MiB | sx 32 KiB | rq 32 KiB
  char* ws = (char*)d_ws;
  s8* xq = (s8*)ws;
  s8* wq8 = (s8*)(ws + (size_t)M_TOK * KDIM);
  float* sx = (float*)(ws + (size_t)M_TOK * KDIM + (size_t)NDIM * KDIM);
  float* rq = (float*)(ws + (size_t)M_TOK * KDIM + (size_t)NDIM * KDIM +
                       (size_t)M_TOK * 4);

  (void)hipFuncSetAttribute((const void*)qlin_gemm_kernel,
                            hipFuncAttributeMaxDynamicSharedMemorySize,
                            49152);

  convert_x_kernel<<<M_TOK, 256, 0, stream>>>(x, xq, sx, rq);
  convert_w_kernel<<<(NDIM * (size_t)KDIM) / (256 * 16), 256, 0, stream>>>(
      wq, wq8);

  qlin_gemm_kernel<<<dim3((M_TOK / 256) * (NDIM / 128)), dim3(256), 49152,
                     stream>>>((const u8*)xq, (const u8*)wq8, sx, rq, scale,
                               zp, bias, out);
}